// Round 3
// baseline (1247.847 us; speedup 1.0000x reference)
//
#include <hip/hip_runtime.h>
#include <hip/hip_bf16.h>

// NonLocalBlock: x[8,64,512,512] f32
//  K1: avgpool 8x8 -> u[B=8][C=64][N=4096]  (f32, ws)
//  K2: theta/phi (pixel-major bf16 [B][N][64]) and gT (channel-major bf16 [B][64][N])
//      v3: lane=n, U row in regs, scalar (SMEM) W loads, LDS-transpose epilogue.
//  K3: flash attention (bf16 MFMA 16x16x32, fp32 accum, no max-subtract) -> y[B][N][64] f32
//      v3: 32 rows/wave (128-row blocks, grid 256): Ph/Gt fragments read once per ct
//          and reused across 2 row-groups -> LDS bytes/row 1.5->0.875 KB. Th LDS dropped
//          (A-frags direct from L2-hot global). Keeps v2's 1-barrier double-buffer.
//  K4: conv1x1(Wc)+bias + nearest-upsample x8 -> out[8,64,512,512] f32
// ws usage: u 8MB | th 4MB | ph 4MB | gT 4MB | y 8MB  = 28MB total

typedef short short8 __attribute__((ext_vector_type(8)));
typedef float floatx4 __attribute__((ext_vector_type(4)));

__device__ inline unsigned short f2bf(float f) {
    union { float f; unsigned int u; } v; v.f = f;
    unsigned int u = v.u;
    u += 0x7fff + ((u >> 16) & 1);   // RNE; inputs are finite
    return (unsigned short)(u >> 16);
}

// sum across the 16 lanes of a DPP row (quad group) via row_ror butterfly — VALU only.
__device__ inline float rowsum16(float x) {
    x += __int_as_float(__builtin_amdgcn_update_dpp(0, __float_as_int(x), 0x121, 0xf, 0xf, false));
    x += __int_as_float(__builtin_amdgcn_update_dpp(0, __float_as_int(x), 0x122, 0xf, 0xf, false));
    x += __int_as_float(__builtin_amdgcn_update_dpp(0, __float_as_int(x), 0x124, 0xf, 0xf, false));
    x += __int_as_float(__builtin_amdgcn_update_dpp(0, __float_as_int(x), 0x128, 0xf, 0xf, false));
    return x;
}

// ---------------- K1: avgpool 8x8, stride 8 ----------------
__global__ __launch_bounds__(256) void k_pool(const float* __restrict__ x,
                                              float* __restrict__ u) {
    int id = blockIdx.x * 256 + threadIdx.x;      // 8*64*64*64 = 2097152
    int ow = id & 63;
    int oh = (id >> 6) & 63;
    int bc = id >> 12;                             // b*64 + c
    const float* p = x + ((size_t)bc * 512 + oh * 8) * 512 + ow * 8;
    float s = 0.f;
#pragma unroll
    for (int r = 0; r < 8; ++r) {
        const float4* q = (const float4*)(p + r * 512);
        float4 a = q[0], b = q[1];
        s += a.x + a.y + a.z + a.w + b.x + b.y + b.z + b.w;
    }
    u[id] = s * (1.f / 64.f);
}

// ---------------- K2: theta/phi/g 1x1 convs (v3) ----------------
__global__ __launch_bounds__(256) void k_qkv(const float* __restrict__ u,
    const float* __restrict__ Wt, const float* __restrict__ bt,
    const float* __restrict__ Wp, const float* __restrict__ bp,
    const float* __restrict__ Wg, const float* __restrict__ bg,
    unsigned short* __restrict__ th, unsigned short* __restrict__ ph,
    unsigned short* __restrict__ gT) {
    __shared__ float U[64 * 68];      // phase 1: U[n][cin] f32; phase 2 (reused): T[n][68] u32
    int b = blockIdx.x >> 6;
    int n0 = (blockIdx.x & 63) * 64;
    int t = threadIdx.x;
    int lane = t & 63, wv = t >> 6;
    // stage u transposed (coalesced float4 reads along n)
#pragma unroll
    for (int i = 0; i < 4; ++i) {
        int f4 = t + 256 * i;                     // 0..1023
        int cin = f4 >> 4, pos = f4 & 15;
        float4 v = *(const float4*)(u + ((size_t)(b * 64 + cin)) * 4096 + n0 + pos * 4);
        U[(pos * 4 + 0) * 68 + cin] = v.x;
        U[(pos * 4 + 1) * 68 + cin] = v.y;
        U[(pos * 4 + 2) * 68 + cin] = v.z;
        U[(pos * 4 + 3) * 68 + cin] = v.w;
    }
    __syncthreads();
    float4 ur[16];
#pragma unroll
    for (int q = 0; q < 16; ++q) ur[q] = *(const float4*)&U[lane * 68 + q * 4];
    __syncthreads();                  // everyone holds its U row in regs; LDS now reusable
    unsigned* T = (unsigned*)U;       // T[n][68] u32: cols 0-31 th pairs, 32-63 ph pairs
    int cb = __builtin_amdgcn_readfirstlane(wv * 16);
    size_t gbase = (size_t)(b * 64) * 4096 + n0 + lane;
    float atp = 0.f, app = 0.f;       // even-i results held for bf16 pairing
#pragma unroll 2
    for (int i = 0; i < 16; ++i) {
        int cout = cb + i;            // wave-uniform -> scalar loads below
        const float* wt = Wt + cout * 64;
        const float* wp = Wp + cout * 64;
        const float* wg = Wg + cout * 64;
        float t0 = bt[cout], t1 = 0.f;
        float q0 = bp[cout], q1 = 0.f;
        float g0 = bg[cout], g1 = 0.f;
#pragma unroll
        for (int q = 0; q < 16; ++q) {
            float4 x = ur[q];
            if (q & 1) {
                t1 = fmaf(wt[4*q+3], x.w, fmaf(wt[4*q+2], x.z, fmaf(wt[4*q+1], x.y, fmaf(wt[4*q], x.x, t1))));
                q1 = fmaf(wp[4*q+3], x.w, fmaf(wp[4*q+2], x.z, fmaf(wp[4*q+1], x.y, fmaf(wp[4*q], x.x, q1))));
                g1 = fmaf(wg[4*q+3], x.w, fmaf(wg[4*q+2], x.z, fmaf(wg[4*q+1], x.y, fmaf(wg[4*q], x.x, g1))));
            } else {
                t0 = fmaf(wt[4*q+3], x.w, fmaf(wt[4*q+2], x.z, fmaf(wt[4*q+1], x.y, fmaf(wt[4*q], x.x, t0))));
                q0 = fmaf(wp[4*q+3], x.w, fmaf(wp[4*q+2], x.z, fmaf(wp[4*q+1], x.y, fmaf(wp[4*q], x.x, q0))));
                g0 = fmaf(wg[4*q+3], x.w, fmaf(wg[4*q+2], x.z, fmaf(wg[4*q+1], x.y, fmaf(wg[4*q], x.x, g0))));
            }
        }
        float at = t0 + t1, ap = q0 + q1, ag = g0 + g1;
        gT[gbase + (size_t)cout * 4096] = f2bf(ag);   // lane=n: coalesced b16 store
        if (i & 1) {
            T[lane * 68 + wv * 8 + (i >> 1)]      = (unsigned)f2bf(atp) | ((unsigned)f2bf(at) << 16);
            T[lane * 68 + 32 + wv * 8 + (i >> 1)] = (unsigned)f2bf(app) | ((unsigned)f2bf(ap) << 16);
        } else { atp = at; app = ap; }
    }
    __syncthreads();
    // transpose readout: coalesced b128 global stores of th/ph rows
#pragma unroll
    for (int j = 0; j < 2; ++j) {
        int qi = t + 256 * j;                    // 0..511
        int r = qi >> 3, c4 = qi & 7;
        uint4 vt = *(const uint4*)&T[r * 68 + c4 * 4];
        uint4 vp = *(const uint4*)&T[r * 68 + 32 + c4 * 4];
        size_t o = ((size_t)(b * 4096 + n0 + r)) * 64 + c4 * 8;
        *(uint4*)(th + o) = vt;
        *(uint4*)(ph + o) = vp;
    }
}

// ---------------- K3: flash attention, bf16 MFMA (v3: 32 rows/wave) ----------------
// S = theta @ phi^T (per batch, N=4096, d=64); P = exp(S) (no max-subtract,
// logits bounded); Y = P @ g; y = Y / rowsum.
// Frag layouts (verified m89/m120): A/B: row=lane&15, k=(lane>>4)*8+j.
// C/D: col=lane&15, row=(lane>>4)*4+reg.
// Block: 128 n-rows, 4 waves x 32 rows (2 row-groups each). Per mt-iter:
//   prefetch tile mt+1 to regs; per ct: read Ph b-frags ONCE, S-MFMA both rg;
//   exp -> Pl; DPP rowsum; Pl reads; per ct: read Gt ONCE, PV-MFMA both rg;
//   ds_write prefetch -> buf[cur^1]; ONE __syncthreads; flip.
__global__ __launch_bounds__(256) void k_attn(
    const unsigned short* __restrict__ th,
    const unsigned short* __restrict__ ph,
    const unsigned short* __restrict__ gT,
    float* __restrict__ y) {
    __shared__ unsigned short Ph[2][64 * 72];   // double-buffered, stride 72
    __shared__ unsigned short Gt[2][64 * 72];   // [c][m], double-buffered
    __shared__ unsigned short Pl[4][32 * 72];   // per-wave P tile (32 rows)
    int b = blockIdx.x >> 5;
    int n0 = (blockIdx.x & 31) * 128;
    int t = threadIdx.x;
    int wave = t >> 6, lane = t & 63, quad = lane >> 4, l16 = lane & 15;
    int row = t >> 2, cg = t & 3;            // staging map: 4 lanes x 2 short8 per 64-elem row

    // A-frags (theta) direct from global: L2-hot, once per block
    short8 a[2][2];
#pragma unroll
    for (int rg = 0; rg < 2; ++rg) {
        const unsigned short* src = th + ((size_t)(b * 4096 + n0 + wave * 32 + rg * 16 + l16)) * 64;
        a[rg][0] = *(const short8*)(src + quad * 8);
        a[rg][1] = *(const short8*)(src + 32 + quad * 8);
    }
    // stage tile 0 of Ph/Gt
    {
        const unsigned short* sp = ph + ((size_t)(b * 4096 + row)) * 64;
        *(short8*)(Ph[0] + row * 72 + cg * 8)      = *(const short8*)(sp + cg * 8);
        *(short8*)(Ph[0] + row * 72 + 32 + cg * 8) = *(const short8*)(sp + 32 + cg * 8);
        const unsigned short* sg = gT + ((size_t)(b * 64 + row)) * 4096;
        *(short8*)(Gt[0] + row * 72 + cg * 8)      = *(const short8*)(sg + cg * 8);
        *(short8*)(Gt[0] + row * 72 + 32 + cg * 8) = *(const short8*)(sg + 32 + cg * 8);
    }
    __syncthreads();

    floatx4 Yacc[2][4];
#pragma unroll
    for (int rg = 0; rg < 2; ++rg)
#pragma unroll
        for (int ct = 0; ct < 4; ++ct) Yacc[rg][ct] = (floatx4){0.f, 0.f, 0.f, 0.f};
    float l[2][4] = {{0.f,0.f,0.f,0.f},{0.f,0.f,0.f,0.f}};

    int cur = 0;
    for (int mt = 0; mt < 64; ++mt) {
        // prefetch next tile into registers (wraps on last iter; harmless reload)
        int mn = ((mt + 1) & 63) * 64;
        short8 r0, r1, r2, r3;
        {
            const unsigned short* sp = ph + ((size_t)(b * 4096 + mn + row)) * 64;
            r0 = *(const short8*)(sp + cg * 8);
            r1 = *(const short8*)(sp + 32 + cg * 8);
            const unsigned short* sg = gT + ((size_t)(b * 64 + row)) * 4096 + mn;
            r2 = *(const short8*)(sg + cg * 8);
            r3 = *(const short8*)(sg + 32 + cg * 8);
        }
        const unsigned short* PhC = Ph[cur];
        const unsigned short* GtC = Gt[cur];

        float psum[2][4] = {{0.f,0.f,0.f,0.f},{0.f,0.f,0.f,0.f}};
#pragma unroll
        for (int ct = 0; ct < 4; ++ct) {
            short8 b0 = *(const short8*)(PhC + (ct * 16 + l16) * 72 + quad * 8);
            short8 b1 = *(const short8*)(PhC + (ct * 16 + l16) * 72 + 32 + quad * 8);
#pragma unroll
            for (int rg = 0; rg < 2; ++rg) {
                floatx4 acc = (floatx4){0.f, 0.f, 0.f, 0.f};
                __builtin_amdgcn_s_setprio(1);
                acc = __builtin_amdgcn_mfma_f32_16x16x32_bf16(a[rg][0], b0, acc, 0, 0, 0);
                acc = __builtin_amdgcn_mfma_f32_16x16x32_bf16(a[rg][1], b1, acc, 0, 0, 0);
                __builtin_amdgcn_s_setprio(0);
#pragma unroll
                for (int r = 0; r < 4; ++r) {
                    float e = __expf(acc[r]);
                    psum[rg][r] += e;
                    // C-layout -> A-layout via wave-private LDS round trip
                    Pl[wave][(rg * 16 + quad * 4 + r) * 72 + ct * 16 + l16] = f2bf(e);
                }
            }
        }
        // f32 row-sum across the 16 lanes holding each row (DPP, VALU pipe)
#pragma unroll
        for (int rg = 0; rg < 2; ++rg)
#pragma unroll
            for (int r = 0; r < 4; ++r) l[rg][r] += rowsum16(psum[rg][r]);
        short8 p[2][2];
#pragma unroll
        for (int rg = 0; rg < 2; ++rg) {
            p[rg][0] = *(const short8*)(Pl[wave] + (rg * 16 + l16) * 72 + quad * 8);
            p[rg][1] = *(const short8*)(Pl[wave] + (rg * 16 + l16) * 72 + 32 + quad * 8);
        }
        __builtin_amdgcn_s_setprio(1);
#pragma unroll
        for (int ct = 0; ct < 4; ++ct) {
            short8 g0 = *(const short8*)(GtC + (ct * 16 + l16) * 72 + quad * 8);
            short8 g1 = *(const short8*)(GtC + (ct * 16 + l16) * 72 + 32 + quad * 8);
#pragma unroll
            for (int rg = 0; rg < 2; ++rg) {
                Yacc[rg][ct] = __builtin_amdgcn_mfma_f32_16x16x32_bf16(p[rg][0], g0, Yacc[rg][ct], 0, 0, 0);
                Yacc[rg][ct] = __builtin_amdgcn_mfma_f32_16x16x32_bf16(p[rg][1], g1, Yacc[rg][ct], 0, 0, 0);
            }
        }
        __builtin_amdgcn_s_setprio(0);
        // land prefetched tile into the other buffer; single barrier publishes it
        unsigned short* PhN = Ph[cur ^ 1];
        unsigned short* GtN = Gt[cur ^ 1];
        *(short8*)(PhN + row * 72 + cg * 8)      = r0;
        *(short8*)(PhN + row * 72 + 32 + cg * 8) = r1;
        *(short8*)(GtN + row * 72 + cg * 8)      = r2;
        *(short8*)(GtN + row * 72 + 32 + cg * 8) = r3;
        __syncthreads();
        cur ^= 1;
    }
    // epilogue: y[b][n][c] = Yacc / l
#pragma unroll
    for (int rg = 0; rg < 2; ++rg)
#pragma unroll
        for (int ct = 0; ct < 4; ++ct)
#pragma unroll
            for (int r = 0; r < 4; ++r) {
                int rr = n0 + wave * 32 + rg * 16 + quad * 4 + r;
                y[((size_t)(b * 4096 + rr)) * 64 + ct * 16 + l16] = Yacc[rg][ct][r] / l[rg][r];
            }
}

// ---------------- K4: conv1x1(Wc) + nearest upsample x8 ----------------
__global__ __launch_bounds__(256) void k_out(const float* __restrict__ y,
    const float* __restrict__ Wc, const float* __restrict__ bc,
    float* __restrict__ out) {
    __shared__ float Y[64 * 66];             // [cin][w], stride 66
    int b = blockIdx.x >> 6;
    int oh = blockIdx.x & 63;
    int t = threadIdx.x;
#pragma unroll
    for (int i = 0; i < 4; ++i) {
        int f4 = t + 256 * i;                // 0..1023
        int w = f4 >> 4, cgp = f4 & 15;
        float4 v = *(const float4*)(y + ((size_t)(b * 4096 + oh * 64 + w)) * 64 + cgp * 4);
        Y[(cgp * 4 + 0) * 66 + w] = v.x;
        Y[(cgp * 4 + 1) * 66 + w] = v.y;
        Y[(cgp * 4 + 2) * 66 + w] = v.z;
        Y[(cgp * 4 + 3) * 66 + w] = v.w;
    }
    __syncthreads();
    int w = t & 63, wv = t >> 6;
#pragma unroll 2
    for (int i = 0; i < 16; ++i) {
        int c = wv + 4 * i;                  // uniform per wave -> scalar Wc row
        float acc = bc[c];
#pragma unroll
        for (int cin = 0; cin < 64; ++cin)
            acc += Wc[c * 64 + cin] * Y[cin * 66 + w];
        float4 v4 = {acc, acc, acc, acc};
        float* base = out + (((size_t)(b * 64 + c)) * 512 + oh * 8) * 512 + w * 8;
#pragma unroll
        for (int r = 0; r < 8; ++r) {
            *(float4*)(base + (size_t)r * 512) = v4;
            *(float4*)(base + (size_t)r * 512 + 4) = v4;
        }
    }
}

extern "C" void kernel_launch(void* const* d_in, const int* in_sizes, int n_in,
                              void* d_out, int out_size, void* d_ws, size_t ws_size,
                              hipStream_t stream) {
    const float* x  = (const float*)d_in[0];
    const float* Wt = (const float*)d_in[1];
    const float* bt = (const float*)d_in[2];
    const float* Wp = (const float*)d_in[3];
    const float* bp = (const float*)d_in[4];
    const float* Wg = (const float*)d_in[5];
    const float* bg = (const float*)d_in[6];
    const float* Wc = (const float*)d_in[7];
    const float* bc = (const float*)d_in[8];
    float* out = (float*)d_out;
    char* ws = (char*)d_ws;
    float* u            = (float*)(ws);                       // 8 MB
    unsigned short* th  = (unsigned short*)(ws + (8  << 20)); // 4 MB
    unsigned short* ph  = (unsigned short*)(ws + (12 << 20)); // 4 MB
    unsigned short* gT  = (unsigned short*)(ws + (16 << 20)); // 4 MB
    float* y            = (float*)(ws + (20 << 20));          // 8 MB

    hipLaunchKernelGGL(k_pool, dim3(8192), dim3(256), 0, stream, x, u);
    hipLaunchKernelGGL(k_qkv,  dim3(512),  dim3(256), 0, stream,
                       u, Wt, bt, Wp, bp, Wg, bg, th, ph, gT);
    hipLaunchKernelGGL(k_attn, dim3(256),  dim3(256), 0, stream, th, ph, gT, y);
    hipLaunchKernelGGL(k_out,  dim3(512),  dim3(256), 0, stream, y, Wc, bc, out);
}

// Round 4
// 1232.966 us; speedup vs baseline: 1.0121x; 1.0121x over previous
//
#include <hip/hip_runtime.h>
#include <hip/hip_bf16.h>

// NonLocalBlock: x[8,64,512,512] f32
//  K1: avgpool 8x8 -> u[B=8][C=64][N=4096]  (f32, ws)
//  K2: theta/phi (pixel-major bf16 [B][N][64]) and gT (channel-major bf16 [B][64][N])
//      v3: lane=n, U row in regs, scalar (SMEM) W loads, LDS-transpose epilogue.
//  K3: flash attention (bf16 MFMA 16x16x32, fp32 accum, no max-subtract) -> y[B][N][64] f32
//      v2 (REVERTED from v3): 16 rows/wave, 64-row blocks, grid 512 (2 blocks/CU =
//      8 waves/CU; v3's 32 rows/wave at 1 wave/SIMD exposed DS latency, +12.7 us).
//      Double-buffered Ph/Gt + register prefetch (1 barrier/iter), DPP rowsum, setprio.
//  K4: conv1x1(Wc)+bias + nearest-upsample x8 -> out[8,64,512,512] f32
// ws usage: u 8MB | th 4MB | ph 4MB | gT 4MB | y 8MB  = 28MB total

typedef short short8 __attribute__((ext_vector_type(8)));
typedef float floatx4 __attribute__((ext_vector_type(4)));

__device__ inline unsigned short f2bf(float f) {
    union { float f; unsigned int u; } v; v.f = f;
    unsigned int u = v.u;
    u += 0x7fff + ((u >> 16) & 1);   // RNE; inputs are finite
    return (unsigned short)(u >> 16);
}

// sum across the 16 lanes of a DPP row (quad group) via row_ror butterfly — VALU only.
__device__ inline float rowsum16(float x) {
    x += __int_as_float(__builtin_amdgcn_update_dpp(0, __float_as_int(x), 0x121, 0xf, 0xf, false));
    x += __int_as_float(__builtin_amdgcn_update_dpp(0, __float_as_int(x), 0x122, 0xf, 0xf, false));
    x += __int_as_float(__builtin_amdgcn_update_dpp(0, __float_as_int(x), 0x124, 0xf, 0xf, false));
    x += __int_as_float(__builtin_amdgcn_update_dpp(0, __float_as_int(x), 0x128, 0xf, 0xf, false));
    return x;
}

// ---------------- K1: avgpool 8x8, stride 8 ----------------
__global__ __launch_bounds__(256) void k_pool(const float* __restrict__ x,
                                              float* __restrict__ u) {
    int id = blockIdx.x * 256 + threadIdx.x;      // 8*64*64*64 = 2097152
    int ow = id & 63;
    int oh = (id >> 6) & 63;
    int bc = id >> 12;                             // b*64 + c
    const float* p = x + ((size_t)bc * 512 + oh * 8) * 512 + ow * 8;
    float s = 0.f;
#pragma unroll
    for (int r = 0; r < 8; ++r) {
        const float4* q = (const float4*)(p + r * 512);
        float4 a = q[0], b = q[1];
        s += a.x + a.y + a.z + a.w + b.x + b.y + b.z + b.w;
    }
    u[id] = s * (1.f / 64.f);
}

// ---------------- K2: theta/phi/g 1x1 convs (v3) ----------------
__global__ __launch_bounds__(256) void k_qkv(const float* __restrict__ u,
    const float* __restrict__ Wt, const float* __restrict__ bt,
    const float* __restrict__ Wp, const float* __restrict__ bp,
    const float* __restrict__ Wg, const float* __restrict__ bg,
    unsigned short* __restrict__ th, unsigned short* __restrict__ ph,
    unsigned short* __restrict__ gT) {
    __shared__ float U[64 * 68];      // phase 1: U[n][cin] f32; phase 2 (reused): T[n][68] u32
    int b = blockIdx.x >> 6;
    int n0 = (blockIdx.x & 63) * 64;
    int t = threadIdx.x;
    int lane = t & 63, wv = t >> 6;
    // stage u transposed (coalesced float4 reads along n)
#pragma unroll
    for (int i = 0; i < 4; ++i) {
        int f4 = t + 256 * i;                     // 0..1023
        int cin = f4 >> 4, pos = f4 & 15;
        float4 v = *(const float4*)(u + ((size_t)(b * 64 + cin)) * 4096 + n0 + pos * 4);
        U[(pos * 4 + 0) * 68 + cin] = v.x;
        U[(pos * 4 + 1) * 68 + cin] = v.y;
        U[(pos * 4 + 2) * 68 + cin] = v.z;
        U[(pos * 4 + 3) * 68 + cin] = v.w;
    }
    __syncthreads();
    float4 ur[16];
#pragma unroll
    for (int q = 0; q < 16; ++q) ur[q] = *(const float4*)&U[lane * 68 + q * 4];
    __syncthreads();                  // everyone holds its U row in regs; LDS now reusable
    unsigned* T = (unsigned*)U;       // T[n][68] u32: cols 0-31 th pairs, 32-63 ph pairs
    int cb = __builtin_amdgcn_readfirstlane(wv * 16);
    size_t gbase = (size_t)(b * 64) * 4096 + n0 + lane;
    float atp = 0.f, app = 0.f;       // even-i results held for bf16 pairing
#pragma unroll 2
    for (int i = 0; i < 16; ++i) {
        int cout = cb + i;            // wave-uniform -> scalar loads below
        const float* wt = Wt + cout * 64;
        const float* wp = Wp + cout * 64;
        const float* wg = Wg + cout * 64;
        float t0 = bt[cout], t1 = 0.f;
        float q0 = bp[cout], q1 = 0.f;
        float g0 = bg[cout], g1 = 0.f;
#pragma unroll
        for (int q = 0; q < 16; ++q) {
            float4 x = ur[q];
            if (q & 1) {
                t1 = fmaf(wt[4*q+3], x.w, fmaf(wt[4*q+2], x.z, fmaf(wt[4*q+1], x.y, fmaf(wt[4*q], x.x, t1))));
                q1 = fmaf(wp[4*q+3], x.w, fmaf(wp[4*q+2], x.z, fmaf(wp[4*q+1], x.y, fmaf(wp[4*q], x.x, q1))));
                g1 = fmaf(wg[4*q+3], x.w, fmaf(wg[4*q+2], x.z, fmaf(wg[4*q+1], x.y, fmaf(wg[4*q], x.x, g1))));
            } else {
                t0 = fmaf(wt[4*q+3], x.w, fmaf(wt[4*q+2], x.z, fmaf(wt[4*q+1], x.y, fmaf(wt[4*q], x.x, t0))));
                q0 = fmaf(wp[4*q+3], x.w, fmaf(wp[4*q+2], x.z, fmaf(wp[4*q+1], x.y, fmaf(wp[4*q], x.x, q0))));
                g0 = fmaf(wg[4*q+3], x.w, fmaf(wg[4*q+2], x.z, fmaf(wg[4*q+1], x.y, fmaf(wg[4*q], x.x, g0))));
            }
        }
        float at = t0 + t1, ap = q0 + q1, ag = g0 + g1;
        gT[gbase + (size_t)cout * 4096] = f2bf(ag);   // lane=n: coalesced b16 store
        if (i & 1) {
            T[lane * 68 + wv * 8 + (i >> 1)]      = (unsigned)f2bf(atp) | ((unsigned)f2bf(at) << 16);
            T[lane * 68 + 32 + wv * 8 + (i >> 1)] = (unsigned)f2bf(app) | ((unsigned)f2bf(ap) << 16);
        } else { atp = at; app = ap; }
    }
    __syncthreads();
    // transpose readout: coalesced b128 global stores of th/ph rows
#pragma unroll
    for (int j = 0; j < 2; ++j) {
        int qi = t + 256 * j;                    // 0..511
        int r = qi >> 3, c4 = qi & 7;
        uint4 vt = *(const uint4*)&T[r * 68 + c4 * 4];
        uint4 vp = *(const uint4*)&T[r * 68 + 32 + c4 * 4];
        size_t o = ((size_t)(b * 4096 + n0 + r)) * 64 + c4 * 8;
        *(uint4*)(th + o) = vt;
        *(uint4*)(ph + o) = vp;
    }
}

// ---------------- K3: flash attention, bf16 MFMA (v2) ----------------
// S = theta @ phi^T (per batch, N=4096, d=64); P = exp(S) (no max-subtract,
// logits bounded); Y = P @ g; y = Y / rowsum.
// Frag layouts (verified m89/m120): A/B: row=lane&15, k=(lane>>4)*8+j.
// C/D: col=lane&15, row=(lane>>4)*4+reg.
// v2 schedule per mt-iter:
//   issue global loads for tile mt+1 into regs        (latency hides under compute)
//   S-MFMA from Ph[cur] -> exp -> Pl round trip -> PV-MFMA from Gt[cur]
//   ds_write regs -> buf[cur^1]; ONE __syncthreads; flip.
// Hazards: writes go to the buffer read two iters ago; the end-of-iter barrier of
// iter mt-1 separates those reads from this iter's writes. Pl is wave-private
// (in-wave DS order + the barrier's lgkmcnt(0) drain protect RAW/WAR).
__global__ __launch_bounds__(256) void k_attn(
    const unsigned short* __restrict__ th,
    const unsigned short* __restrict__ ph,
    const unsigned short* __restrict__ gT,
    float* __restrict__ y) {
    __shared__ unsigned short Th[64 * 72];      // stride 72 (144B: 2-way-conflict b128 reads)
    __shared__ unsigned short Ph[2][64 * 72];   // double-buffered
    __shared__ unsigned short Gt[2][64 * 72];   // [c][m], double-buffered
    __shared__ unsigned short Pl[4 * 16 * 72];  // per-wave P tile
    int b = blockIdx.x >> 6;
    int n0 = (blockIdx.x & 63) * 64;
    int t = threadIdx.x;
    int wave = t >> 6, lane = t & 63, quad = lane >> 4, l16 = lane & 15;
    int row = t >> 2, cg = t & 3;            // staging map: 4 lanes x 2 short8 per 64-elem row

    // prologue: stage Th + tile 0 of Ph/Gt, single barrier
    {
        const unsigned short* src = th + ((size_t)(b * 4096 + n0 + row)) * 64;
        *(short8*)(Th + row * 72 + cg * 8)      = *(const short8*)(src + cg * 8);
        *(short8*)(Th + row * 72 + 32 + cg * 8) = *(const short8*)(src + 32 + cg * 8);
        const unsigned short* sp = ph + ((size_t)(b * 4096 + row)) * 64;
        *(short8*)(Ph[0] + row * 72 + cg * 8)      = *(const short8*)(sp + cg * 8);
        *(short8*)(Ph[0] + row * 72 + 32 + cg * 8) = *(const short8*)(sp + 32 + cg * 8);
        const unsigned short* sg = gT + ((size_t)(b * 64 + row)) * 4096;
        *(short8*)(Gt[0] + row * 72 + cg * 8)      = *(const short8*)(sg + cg * 8);
        *(short8*)(Gt[0] + row * 72 + 32 + cg * 8) = *(const short8*)(sg + 32 + cg * 8);
    }
    __syncthreads();
    short8 a0 = *(const short8*)(Th + (wave * 16 + l16) * 72 + quad * 8);
    short8 a1 = *(const short8*)(Th + (wave * 16 + l16) * 72 + 32 + quad * 8);

    floatx4 Yacc[4];
#pragma unroll
    for (int ct = 0; ct < 4; ++ct) Yacc[ct] = (floatx4){0.f, 0.f, 0.f, 0.f};
    float l[4] = {0.f, 0.f, 0.f, 0.f};

    int cur = 0;
    for (int mt = 0; mt < 64; ++mt) {
        // prefetch next tile into registers (wraps on last iter; harmless reload)
        int mn = ((mt + 1) & 63) * 64;
        short8 r0, r1, r2, r3;
        {
            const unsigned short* sp = ph + ((size_t)(b * 4096 + mn + row)) * 64;
            r0 = *(const short8*)(sp + cg * 8);
            r1 = *(const short8*)(sp + 32 + cg * 8);
            const unsigned short* sg = gT + ((size_t)(b * 64 + row)) * 4096 + mn;
            r2 = *(const short8*)(sg + cg * 8);
            r3 = *(const short8*)(sg + 32 + cg * 8);
        }
        const unsigned short* PhC = Ph[cur];
        const unsigned short* GtC = Gt[cur];

        float psum[4] = {0.f, 0.f, 0.f, 0.f};
#pragma unroll
        for (int ct = 0; ct < 4; ++ct) {
            short8 b0 = *(const short8*)(PhC + (ct * 16 + l16) * 72 + quad * 8);
            short8 b1 = *(const short8*)(PhC + (ct * 16 + l16) * 72 + 32 + quad * 8);
            floatx4 acc = (floatx4){0.f, 0.f, 0.f, 0.f};
            __builtin_amdgcn_s_setprio(1);
            acc = __builtin_amdgcn_mfma_f32_16x16x32_bf16(a0, b0, acc, 0, 0, 0);
            acc = __builtin_amdgcn_mfma_f32_16x16x32_bf16(a1, b1, acc, 0, 0, 0);
            __builtin_amdgcn_s_setprio(0);
#pragma unroll
            for (int r = 0; r < 4; ++r) {
                float e = __expf(acc[r]);
                psum[r] += e;
                // C-layout -> A-layout via wave-private LDS round trip
                Pl[wave * 16 * 72 + (quad * 4 + r) * 72 + ct * 16 + l16] = f2bf(e);
            }
        }
        // f32 row-sum across the 16 lanes holding each row (DPP, VALU pipe)
#pragma unroll
        for (int r = 0; r < 4; ++r) l[r] += rowsum16(psum[r]);
        short8 p0 = *(const short8*)(Pl + wave * 16 * 72 + l16 * 72 + quad * 8);
        short8 p1 = *(const short8*)(Pl + wave * 16 * 72 + l16 * 72 + 32 + quad * 8);
        __builtin_amdgcn_s_setprio(1);
#pragma unroll
        for (int ct = 0; ct < 4; ++ct) {
            short8 g0 = *(const short8*)(GtC + (ct * 16 + l16) * 72 + quad * 8);
            short8 g1 = *(const short8*)(GtC + (ct * 16 + l16) * 72 + 32 + quad * 8);
            Yacc[ct] = __builtin_amdgcn_mfma_f32_16x16x32_bf16(p0, g0, Yacc[ct], 0, 0, 0);
            Yacc[ct] = __builtin_amdgcn_mfma_f32_16x16x32_bf16(p1, g1, Yacc[ct], 0, 0, 0);
        }
        __builtin_amdgcn_s_setprio(0);
        // land prefetched tile into the other buffer; single barrier publishes it
        unsigned short* PhN = Ph[cur ^ 1];
        unsigned short* GtN = Gt[cur ^ 1];
        *(short8*)(PhN + row * 72 + cg * 8)      = r0;
        *(short8*)(PhN + row * 72 + 32 + cg * 8) = r1;
        *(short8*)(GtN + row * 72 + cg * 8)      = r2;
        *(short8*)(GtN + row * 72 + 32 + cg * 8) = r3;
        __syncthreads();
        cur ^= 1;
    }
    // epilogue: y[b][n][c] = Yacc / l
#pragma unroll
    for (int ct = 0; ct < 4; ++ct)
#pragma unroll
        for (int r = 0; r < 4; ++r) {
            int rr = n0 + wave * 16 + quad * 4 + r;
            y[((size_t)(b * 4096 + rr)) * 64 + ct * 16 + l16] = Yacc[ct][r] / l[r];
        }
}

// ---------------- K4: conv1x1(Wc) + nearest upsample x8 ----------------
__global__ __launch_bounds__(256) void k_out(const float* __restrict__ y,
    const float* __restrict__ Wc, const float* __restrict__ bc,
    float* __restrict__ out) {
    __shared__ float Y[64 * 66];             // [cin][w], stride 66
    int b = blockIdx.x >> 6;
    int oh = blockIdx.x & 63;
    int t = threadIdx.x;
#pragma unroll
    for (int i = 0; i < 4; ++i) {
        int f4 = t + 256 * i;                // 0..1023
        int w = f4 >> 4, cgp = f4 & 15;
        float4 v = *(const float4*)(y + ((size_t)(b * 4096 + oh * 64 + w)) * 64 + cgp * 4);
        Y[(cgp * 4 + 0) * 66 + w] = v.x;
        Y[(cgp * 4 + 1) * 66 + w] = v.y;
        Y[(cgp * 4 + 2) * 66 + w] = v.z;
        Y[(cgp * 4 + 3) * 66 + w] = v.w;
    }
    __syncthreads();
    int w = t & 63, wv = t >> 6;
#pragma unroll 2
    for (int i = 0; i < 16; ++i) {
        int c = wv + 4 * i;                  // uniform per wave -> scalar Wc row
        float acc = bc[c];
#pragma unroll
        for (int cin = 0; cin < 64; ++cin)
            acc += Wc[c * 64 + cin] * Y[cin * 66 + w];
        float4 v4 = {acc, acc, acc, acc};
        float* base = out + (((size_t)(b * 64 + c)) * 512 + oh * 8) * 512 + w * 8;
#pragma unroll
        for (int r = 0; r < 8; ++r) {
            *(float4*)(base + (size_t)r * 512) = v4;
            *(float4*)(base + (size_t)r * 512 + 4) = v4;
        }
    }
}

extern "C" void kernel_launch(void* const* d_in, const int* in_sizes, int n_in,
                              void* d_out, int out_size, void* d_ws, size_t ws_size,
                              hipStream_t stream) {
    const float* x  = (const float*)d_in[0];
    const float* Wt = (const float*)d_in[1];
    const float* bt = (const float*)d_in[2];
    const float* Wp = (const float*)d_in[3];
    const float* bp = (const float*)d_in[4];
    const float* Wg = (const float*)d_in[5];
    const float* bg = (const float*)d_in[6];
    const float* Wc = (const float*)d_in[7];
    const float* bc = (const float*)d_in[8];
    float* out = (float*)d_out;
    char* ws = (char*)d_ws;
    float* u            = (float*)(ws);                       // 8 MB
    unsigned short* th  = (unsigned short*)(ws + (8  << 20)); // 4 MB
    unsigned short* ph  = (unsigned short*)(ws + (12 << 20)); // 4 MB
    unsigned short* gT  = (unsigned short*)(ws + (16 << 20)); // 4 MB
    float* y            = (float*)(ws + (20 << 20));          // 8 MB

    hipLaunchKernelGGL(k_pool, dim3(8192), dim3(256), 0, stream, x, u);
    hipLaunchKernelGGL(k_qkv,  dim3(512),  dim3(256), 0, stream,
                       u, Wt, bt, Wp, bp, Wg, bg, th, ph, gT);
    hipLaunchKernelGGL(k_attn, dim3(512),  dim3(256), 0, stream, th, ph, gT, y);
    hipLaunchKernelGGL(k_out,  dim3(512),  dim3(256), 0, stream, y, Wc, bc, out);
}